// Round 1
// baseline (623.889 us; speedup 1.0000x reference)
//
#include <hip/hip_runtime.h>

// Problem constants
#define BB 128
#define NN 1152
#define KD 512
#define NC 10
#define ND 16
#define CD 160   // NC*ND

// ws layout: u_hat bf16 [BB*NN][CD] = 147456*160*2 = 47,185,920 bytes

typedef unsigned short ushort_t;
typedef unsigned int uint_t;

__device__ __forceinline__ float bf2f(ushort_t u) {
  return __uint_as_float(((uint_t)u) << 16);
}
__device__ __forceinline__ ushort_t f2bf(float f) {
  uint_t x = __float_as_uint(f);
  x += 0x7fffu + ((x >> 16) & 1u);   // round-to-nearest-even
  return (ushort_t)(x >> 16);
}

// ---------------- GEMM: u_hat[m][j] = sum_k x[m][k] * W[k][j] ----------------
// BM=64 rows, BN=160 (full), BK=32. 256 threads -> 16x16 grid, 4 rows x 10 cols each.
__global__ __launch_bounds__(256) void gemm_uhat(
    const float* __restrict__ x, const float* __restrict__ W,
    ushort_t* __restrict__ uhat) {
  __shared__ float xs[64][33];    // +1 pad
  __shared__ float wsh[32][160];
  const int tid = threadIdx.x;
  const int ty = tid >> 4, tx = tid & 15;
  const int row0 = blockIdx.x * 64;
  const int c0 = tx * 10;
  float acc[4][10];
#pragma unroll
  for (int r = 0; r < 4; ++r)
#pragma unroll
    for (int c = 0; c < NC; ++c) acc[r][c] = 0.f;

  for (int k0 = 0; k0 < KD; k0 += 32) {
    // stage x tile 64x32 (float4 per thread x2)
#pragma unroll
    for (int i = 0; i < 2; ++i) {
      int f = tid + i * 256;          // 0..511
      int r = f >> 3, kq = f & 7;
      float4 v = *reinterpret_cast<const float4*>(
          &x[(size_t)(row0 + r) * KD + k0 + kq * 4]);
      xs[r][kq * 4 + 0] = v.x; xs[r][kq * 4 + 1] = v.y;
      xs[r][kq * 4 + 2] = v.z; xs[r][kq * 4 + 3] = v.w;
    }
    // stage W tile 32x160 (float4 per thread x5)
#pragma unroll
    for (int i = 0; i < 5; ++i) {
      int f = tid + i * 256;          // 0..1279
      int r = f / 40, c4 = f % 40;
      *reinterpret_cast<float4*>(&wsh[r][c4 * 4]) =
          *reinterpret_cast<const float4*>(&W[(size_t)(k0 + r) * CD + c4 * 4]);
    }
    __syncthreads();
#pragma unroll 4
    for (int kk = 0; kk < 32; ++kk) {
      float a0 = xs[ty * 4 + 0][kk], a1 = xs[ty * 4 + 1][kk],
            a2 = xs[ty * 4 + 2][kk], a3 = xs[ty * 4 + 3][kk];
      float w[10];
#pragma unroll
      for (int i = 0; i < 5; ++i) {
        float2 t2 = *reinterpret_cast<const float2*>(&wsh[kk][c0 + 2 * i]);
        w[2 * i] = t2.x; w[2 * i + 1] = t2.y;
      }
#pragma unroll
      for (int c = 0; c < NC; ++c) {
        acc[0][c] += a0 * w[c];
        acc[1][c] += a1 * w[c];
        acc[2][c] += a2 * w[c];
        acc[3][c] += a3 * w[c];
      }
    }
    __syncthreads();
  }
  // store bf16, packed as 5 dwords per row
#pragma unroll
  for (int r = 0; r < 4; ++r) {
    size_t base = (size_t)(row0 + ty * 4 + r) * CD + c0;
    uint_t* p = reinterpret_cast<uint_t*>(uhat + base);
#pragma unroll
    for (int i = 0; i < 5; ++i)
      p[i] = (uint_t)f2bf(acc[r][2 * i]) | ((uint_t)f2bf(acc[r][2 * i + 1]) << 16);
  }
}

// ---------------- Routing: one block per batch ----------------
// 640 threads = 8 n-groups x 80 threads; each thread owns 2 consecutive j.
// Thread t: g=t/80 (n offset), jj=t%80, j=2*jj, cap=j/16.
// 8-thread subgroups (aligned, within-wave) reduce over d (16 elems) via shfl_xor.
#define RT_THREADS 640
#define RG 8

__global__ __launch_bounds__(RT_THREADS) void routing(
    const ushort_t* __restrict__ uhat, float* __restrict__ out) {
  __shared__ float bv[NN][NC];     // routing logits b [1152][10]
  __shared__ float sred[RG][CD];
  __shared__ float sv[CD];
  __shared__ float vv[CD];
  __shared__ float sc[NC];

  const int b = blockIdx.x;
  const int t = threadIdx.x;
  const int g = t / 80;
  const int jj = t % 80;
  const int j = jj * 2;
  const int cap = j >> 4;
  const ushort_t* ub = uhat + (size_t)b * NN * CD;

  auto finalize = [&](float mult) {
    __syncthreads();
    if (t < CD) {
      float s = 0.f;
#pragma unroll
      for (int q = 0; q < RG; ++q) s += sred[q][t];
      sv[t] = s * mult;
    }
    __syncthreads();
    if (t < NC) {
      float ss = 0.f;
#pragma unroll
      for (int d = 0; d < ND; ++d) { float z = sv[t * ND + d]; ss += z * z; }
      float sn = sqrtf(ss) + 1e-7f;
      sc[t] = sn / (1.f + sn * sn);   // v = s * sn/(1+sn^2)
    }
    __syncthreads();
    if (t < CD) vv[t] = sv[t] * sc[t >> 4];
    __syncthreads();
  };

  // ---- Pass A: s0 = 0.1 * sum_n u_hat ; v0 = squash(s0)
  float a0 = 0.f, a1 = 0.f;
  for (int n = g; n < NN; n += RG) {
    ushort2 u = *reinterpret_cast<const ushort2*>(&ub[(size_t)n * CD + j]);
    a0 += bf2f(u.x); a1 += bf2f(u.y);
  }
  sred[g][j] = a0; sred[g][j + 1] = a1;
  finalize(0.1f);

  // ---- Pass B1: b1[n][c] = sum_d u_hat[n,c,d]*v0[c,d]
  for (int n = g; n < NN; n += RG) {
    ushort2 u = *reinterpret_cast<const ushort2*>(&ub[(size_t)n * CD + j]);
    float p = bf2f(u.x) * vv[j] + bf2f(u.y) * vv[j + 1];
    p += __shfl_xor(p, 1);
    p += __shfl_xor(p, 2);
    p += __shfl_xor(p, 4);
    if ((t & 7) == 0) bv[n][cap] = p;
  }
  __syncthreads();
  // ---- Pass B2: c1 = softmax(b1); s1 = sum_n c1*u_hat ; v1
  a0 = 0.f; a1 = 0.f;
  for (int n = g; n < NN; n += RG) {
    float bmax = -3.4e38f;
#pragma unroll
    for (int c = 0; c < NC; ++c) bmax = fmaxf(bmax, bv[n][c]);
    float Z = 0.f, mine = 0.f;
#pragma unroll
    for (int c = 0; c < NC; ++c) {
      float e = __expf(bv[n][c] - bmax);
      Z += e;
      if (c == cap) mine = e;
    }
    float wgt = mine / Z;
    ushort2 u = *reinterpret_cast<const ushort2*>(&ub[(size_t)n * CD + j]);
    a0 += wgt * bf2f(u.x); a1 += wgt * bf2f(u.y);
  }
  sred[g][j] = a0; sred[g][j + 1] = a1;
  finalize(1.f);

  // ---- Pass C1: b2 = b1 + u_hat . v1
  for (int n = g; n < NN; n += RG) {
    ushort2 u = *reinterpret_cast<const ushort2*>(&ub[(size_t)n * CD + j]);
    float p = bf2f(u.x) * vv[j] + bf2f(u.y) * vv[j + 1];
    p += __shfl_xor(p, 1);
    p += __shfl_xor(p, 2);
    p += __shfl_xor(p, 4);
    if ((t & 7) == 0) bv[n][cap] += p;
  }
  __syncthreads();
  // ---- Pass C2: c2 = softmax(b2); s2 ; v2 -> out
  a0 = 0.f; a1 = 0.f;
  for (int n = g; n < NN; n += RG) {
    float bmax = -3.4e38f;
#pragma unroll
    for (int c = 0; c < NC; ++c) bmax = fmaxf(bmax, bv[n][c]);
    float Z = 0.f, mine = 0.f;
#pragma unroll
    for (int c = 0; c < NC; ++c) {
      float e = __expf(bv[n][c] - bmax);
      Z += e;
      if (c == cap) mine = e;
    }
    float wgt = mine / Z;
    ushort2 u = *reinterpret_cast<const ushort2*>(&ub[(size_t)n * CD + j]);
    a0 += wgt * bf2f(u.x); a1 += wgt * bf2f(u.y);
  }
  sred[g][j] = a0; sred[g][j + 1] = a1;
  finalize(1.f);
  if (t < CD) out[(size_t)b * CD + t] = vv[t];
}

extern "C" void kernel_launch(void* const* d_in, const int* in_sizes, int n_in,
                              void* d_out, int out_size, void* d_ws, size_t ws_size,
                              hipStream_t stream) {
  const float* x = (const float*)d_in[0];   // [128,1152,512] f32
  const float* W = (const float*)d_in[1];   // [512,160] f32
  float* out = (float*)d_out;               // [128,10,16] f32
  ushort_t* uhat = (ushort_t*)d_ws;         // 47,185,920 bytes bf16

  gemm_uhat<<<(BB * NN) / 64, 256, 0, stream>>>(x, W, uhat);
  routing<<<BB, RT_THREADS, 0, stream>>>(uhat, out);
}

// Round 2
// 259.732 us; speedup vs baseline: 2.4020x; 2.4020x over previous
//
#include <hip/hip_runtime.h>

#define BB 128
#define NN 1152
#define KD 512
#define NC 10
#define ND 16
#define CD 160   // NC*ND

typedef unsigned short ushort_t;
typedef unsigned int uint_t;
typedef short short8v __attribute__((ext_vector_type(8)));
typedef float float4v __attribute__((ext_vector_type(4)));

__device__ __forceinline__ float bf2f(ushort_t u) {
  return __uint_as_float(((uint_t)u) << 16);
}
__device__ __forceinline__ ushort_t f2bf(float f) {
  uint_t x = __float_as_uint(f);
  x += 0x7fffu + ((x >> 16) & 1u);   // round-to-nearest-even
  return (ushort_t)(x >> 16);
}

// ---------- W transpose+convert: Wt[n][k] = bf16(W[k][n]), [160][512] ----------
__global__ __launch_bounds__(256) void wconv(const float* __restrict__ W,
                                             ushort_t* __restrict__ Wt) {
  int idx = blockIdx.x * 256 + threadIdx.x;   // 81920 total
  int n = idx >> 9, k = idx & 511;
  Wt[idx] = f2bf(W[(size_t)k * CD + n]);
}

// ---------- GEMM via MFMA, no LDS staging ----------
// Block: 256 thr = 4 waves; wave covers 32 rows (2 row-groups of 16) x all 160 cols.
// Block covers 128 rows; grid = 147456/128 = 1152. 1152 rows/batch = 9 blocks/batch.
// A-frag (16x16x32 bf16): lane l holds row (l&15), k = 8*(l>>4)+0..7.
// B-frag: col (l&15), same k pattern -> read 16B contiguous from Wt[col][k..k+7].
// C/D: col = l&15, row = (l>>4)*4 + r  (verified layout, learn_hip m89/m91).
// Epilogue also emits partial col-sums (routing pass A) per block.
__global__ __launch_bounds__(256) void gemm_mfma(
    const float* __restrict__ x, const ushort_t* __restrict__ Wt,
    ushort_t* __restrict__ uhat, float* __restrict__ partials) {
  __shared__ float sA[4][CD];
  const int tid = threadIdx.x;
  const int wave = tid >> 6, lane = tid & 63;
  const int lrow = lane & 15, lg = lane >> 4;      // lg in 0..3
  const int row0 = blockIdx.x * 128 + wave * 32;

  float4v acc[2][10];
#pragma unroll
  for (int rg = 0; rg < 2; ++rg)
#pragma unroll
    for (int nt = 0; nt < 10; ++nt)
#pragma unroll
      for (int r = 0; r < 4; ++r) acc[rg][nt][r] = 0.f;

  const float* xb0 = x + (size_t)(row0 + lrow) * KD + lg * 8;
  const float* xb1 = xb0 + (size_t)16 * KD;
  const ushort_t* wb = Wt + (size_t)lrow * KD + lg * 8;

  for (int k0 = 0; k0 < KD; k0 += 32) {
    short8v a[2];
#pragma unroll
    for (int rg = 0; rg < 2; ++rg) {
      const float* p = (rg ? xb1 : xb0) + k0;
      float4v f0 = *reinterpret_cast<const float4v*>(p);
      float4v f1 = *reinterpret_cast<const float4v*>(p + 4);
      short8v t;
      t[0] = (short)f2bf(f0[0]); t[1] = (short)f2bf(f0[1]);
      t[2] = (short)f2bf(f0[2]); t[3] = (short)f2bf(f0[3]);
      t[4] = (short)f2bf(f1[0]); t[5] = (short)f2bf(f1[1]);
      t[6] = (short)f2bf(f1[2]); t[7] = (short)f2bf(f1[3]);
      a[rg] = t;
    }
#pragma unroll
    for (int nt = 0; nt < 10; ++nt) {
      short8v bfr = *reinterpret_cast<const short8v*>(
          wb + (size_t)nt * 16 * KD + k0);
      acc[0][nt] = __builtin_amdgcn_mfma_f32_16x16x32_bf16(a[0], bfr, acc[0][nt], 0, 0, 0);
      acc[1][nt] = __builtin_amdgcn_mfma_f32_16x16x32_bf16(a[1], bfr, acc[1][nt], 0, 0, 0);
    }
  }

  // store u_hat bf16
#pragma unroll
  for (int rg = 0; rg < 2; ++rg)
#pragma unroll
    for (int nt = 0; nt < 10; ++nt)
#pragma unroll
      for (int r = 0; r < 4; ++r) {
        int row = row0 + rg * 16 + lg * 4 + r;
        uhat[(size_t)row * CD + nt * 16 + lrow] = f2bf(acc[rg][nt][r]);
      }

  // routing pass A partials: sum over this block's 128 rows per col
#pragma unroll
  for (int nt = 0; nt < 10; ++nt) {
    float p = 0.f;
#pragma unroll
    for (int rg = 0; rg < 2; ++rg)
#pragma unroll
      for (int r = 0; r < 4; ++r) p += acc[rg][nt][r];
    p += __shfl_xor(p, 16);
    p += __shfl_xor(p, 32);
    if (lg == 0) sA[wave][nt * 16 + lrow] = p;
  }
  __syncthreads();
  if (tid < CD) {
    float s = sA[0][tid] + sA[1][tid] + sA[2][tid] + sA[3][tid];
    partials[(size_t)blockIdx.x * CD + tid] = s;
  }
}

// ---------- squash: per batch, reduce 9 chunk-partials, squash ----------
// mode 0: vbuf = v (mult=0.1)   mode 1: vbuf += v   mode 2: out = v
__global__ __launch_bounds__(CD) void squash_k(
    const float* __restrict__ partials, float* __restrict__ vbuf,
    float* __restrict__ outp, float mult, int mode) {
  int b = blockIdx.x, t = threadIdx.x;
  float s = 0.f;
#pragma unroll
  for (int ch = 0; ch < 9; ++ch) s += partials[((size_t)b * 9 + ch) * CD + t];
  s *= mult;
  float ss = s * s;
  ss += __shfl_xor(ss, 1); ss += __shfl_xor(ss, 2);
  ss += __shfl_xor(ss, 4); ss += __shfl_xor(ss, 8);
  float sn = sqrtf(ss) + 1e-7f;
  float v = s * sn / (1.f + sn * sn);
  size_t o = (size_t)b * CD + t;
  if (mode == 0) vbuf[o] = v;
  else if (mode == 1) vbuf[o] += v;
  else outp[o] = v;
}

// ---------- routing iteration: one fused pass over a 128-row chunk ----------
// b_i[n,c] = sum_d u_hat[n,c,d]*V[c,d]  (V = v0 or v0+v1; b starts at 0 so
// b2 = u.(v0+v1) -- no b buffer needed). Then softmax over c, accumulate
// partial s = sum_n c[n]*u_hat[n]. u_hat chunk values held in registers
// between phases (single global pass).
#define ITER_T 640
__global__ __launch_bounds__(ITER_T) void iter_k(
    const ushort_t* __restrict__ uhat, const float* __restrict__ vbuf,
    float* __restrict__ partials) {
  __shared__ float bv[128][NC];
  __shared__ float sred[8][CD];
  __shared__ float vv[CD];
  const int blk = blockIdx.x;
  const int b = blk / 9, ch = blk % 9;
  const int t = threadIdx.x;
  const int g = t / 80, jj = t % 80;
  const int j = jj * 2, cap = jj >> 3;
  const ushort_t* ub = uhat + ((size_t)b * NN + ch * 128) * CD;

  if (t < CD) vv[t] = vbuf[(size_t)b * CD + t];
  __syncthreads();

  ushort2 u2[16];
#pragma unroll
  for (int it = 0; it < 16; ++it) {
    int nl = g + it * 8;
    u2[it] = *reinterpret_cast<const ushort2*>(&ub[(size_t)nl * CD + j]);
    float p = bf2f(u2[it].x) * vv[j] + bf2f(u2[it].y) * vv[j + 1];
    p += __shfl_xor(p, 1);
    p += __shfl_xor(p, 2);
    p += __shfl_xor(p, 4);
    if ((t & 7) == 0) bv[nl][cap] = p;
  }
  __syncthreads();

  float a0 = 0.f, a1 = 0.f;
#pragma unroll
  for (int it = 0; it < 16; ++it) {
    int nl = g + it * 8;
    float bm = bv[nl][0];
#pragma unroll
    for (int c = 1; c < NC; ++c) bm = fmaxf(bm, bv[nl][c]);
    float Z = 0.f, mine = 0.f;
#pragma unroll
    for (int c = 0; c < NC; ++c) {
      float e = __expf(bv[nl][c] - bm);
      Z += e;
      if (c == cap) mine = e;
    }
    float w = mine / Z;
    a0 += w * bf2f(u2[it].x);
    a1 += w * bf2f(u2[it].y);
  }
  sred[g][j] = a0; sred[g][j + 1] = a1;
  __syncthreads();
  if (t < CD) {
    float s = 0.f;
#pragma unroll
    for (int q = 0; q < 8; ++q) s += sred[q][t];
    partials[(size_t)blk * CD + t] = s;
  }
}

extern "C" void kernel_launch(void* const* d_in, const int* in_sizes, int n_in,
                              void* d_out, int out_size, void* d_ws, size_t ws_size,
                              hipStream_t stream) {
  const float* x = (const float*)d_in[0];   // [128,1152,512] f32
  const float* W = (const float*)d_in[1];   // [512,160] f32
  float* out = (float*)d_out;               // [128,10,16] f32

  char* ws = (char*)d_ws;
  // ws layout (all 16B-aligned):
  ushort_t* uhat     = (ushort_t*)ws;                        // 47,185,920 B
  ushort_t* Wt       = (ushort_t*)(ws + 47185920);           //    163,840 B
  float*    partials = (float*)(ws + 47185920 + 163840);     //    737,280 B
  float*    vbuf     = (float*)(ws + 47185920 + 163840 + 737280); // 81,920 B

  wconv<<<320, 256, 0, stream>>>(W, Wt);
  gemm_mfma<<<1152, 256, 0, stream>>>(x, Wt, uhat, partials);
  squash_k<<<BB, CD, 0, stream>>>(partials, vbuf, out, 0.1f, 0);  // v0
  iter_k<<<1152, ITER_T, 0, stream>>>(uhat, vbuf, partials);      // s1
  squash_k<<<BB, CD, 0, stream>>>(partials, vbuf, out, 1.f, 1);   // vbuf = v0+v1
  iter_k<<<1152, ITER_T, 0, stream>>>(uhat, vbuf, partials);      // s2
  squash_k<<<BB, CD, 0, stream>>>(partials, vbuf, out, 1.f, 2);   // out = v2
}

// Round 3
// 242.624 us; speedup vs baseline: 2.5714x; 1.0705x over previous
//
#include <hip/hip_runtime.h>

#define BB 128
#define NN 1152
#define KD 512
#define NC 10
#define ND 16
#define CD 160   // NC*ND

typedef unsigned short ushort_t;
typedef unsigned int uint_t;
typedef short short8v __attribute__((ext_vector_type(8)));
typedef float float4v __attribute__((ext_vector_type(4)));

__device__ __forceinline__ float bf2f(ushort_t u) {
  return __uint_as_float(((uint_t)u) << 16);
}
__device__ __forceinline__ ushort_t f2bf(float f) {
  uint_t x = __float_as_uint(f);
  x += 0x7fffu + ((x >> 16) & 1u);   // round-to-nearest-even
  return (ushort_t)(x >> 16);
}

// ---------- W transpose+convert: Wt[n][k] = bf16(W[k][n]), [160][512] ----------
__global__ __launch_bounds__(256) void wconv(const float* __restrict__ W,
                                             ushort_t* __restrict__ Wt) {
  int idx = blockIdx.x * 256 + threadIdx.x;   // 81920 total
  int n = idx >> 9, k = idx & 511;
  Wt[idx] = f2bf(W[(size_t)k * CD + n]);
}

// ---------- GEMM via MFMA, LDS-staged A (coalesced + swizzled) ----------
// BM=64 rows, BK=64, 256 thr = 4 waves; wave w = rows w*16..+16, all 160 cols.
// acc[10] f32x4 = 40 VGPR. Grid 2304 (147456/64), 18 blocks per batch.
// A-frag (16x16x32): lane l row=(l&15), k=kk*32+(l>>4)*8+0..7 (validated r2).
// LDS A tile [64][64] bf16, swizzle byte ^= (row&7)<<4 (write 8B, read 16B).
// Epilogue: C repacked via LDS -> 16B coalesced stores; col-sum partials.
__global__ __launch_bounds__(256) void gemm_mfma(
    const float* __restrict__ x, const ushort_t* __restrict__ Wt,
    ushort_t* __restrict__ uhat, float* __restrict__ partials) {
  __shared__ ushort_t sbuf[64 * 168];     // A-tile (64*64) / C-tile [64][168] union
  __shared__ float sA[4][CD];
  ushort_t* At = sbuf;
  ushort_t* Ct = sbuf;

  const int tid = threadIdx.x;
  const int wave = tid >> 6, lane = tid & 63;
  const int lrow = lane & 15, lg = lane >> 4;
  const int row0 = blockIdx.x * 64;

  float4v acc[10];
#pragma unroll
  for (int nt = 0; nt < 10; ++nt)
#pragma unroll
    for (int r = 0; r < 4; ++r) acc[nt][r] = 0.f;

  const ushort_t* wb = Wt + (size_t)lrow * KD + lg * 8;

  for (int k0 = 0; k0 < KD; k0 += 64) {
    // stage A tile: 64 rows x 64 k, f32 -> bf16, coalesced
#pragma unroll
    for (int i = 0; i < 4; ++i) {
      int f = tid + i * 256;                 // 0..1023
      int row = f >> 4, kq = f & 15;
      float4v v = *reinterpret_cast<const float4v*>(
          &x[(size_t)(row0 + row) * KD + k0 + kq * 4]);
      uint_t lo = (uint_t)f2bf(v[0]) | ((uint_t)f2bf(v[1]) << 16);
      uint_t hi = (uint_t)f2bf(v[2]) | ((uint_t)f2bf(v[3]) << 16);
      int byte = (row << 7) + (kq << 3);
      byte ^= (row & 7) << 4;
      uint2* p = reinterpret_cast<uint2*>(reinterpret_cast<char*>(At) + byte);
      p->x = lo; p->y = hi;
    }
    __syncthreads();
#pragma unroll
    for (int kk = 0; kk < 2; ++kk) {
      int arow = wave * 16 + lrow;
      int abyte = ((arow << 7) + kk * 64 + lg * 16) ^ ((arow & 7) << 4);
      short8v a = *reinterpret_cast<const short8v*>(
          reinterpret_cast<const char*>(At) + abyte);
#pragma unroll
      for (int nt = 0; nt < 10; ++nt) {
        short8v bfr = *reinterpret_cast<const short8v*>(
            wb + (size_t)nt * 16 * KD + k0 + kk * 32);
        acc[nt] = __builtin_amdgcn_mfma_f32_16x16x32_bf16(a, bfr, acc[nt], 0, 0, 0);
      }
    }
    __syncthreads();
  }

  // col-sum partials (routing pass A) over this block's 64 rows
#pragma unroll
  for (int nt = 0; nt < 10; ++nt) {
    float p = acc[nt][0] + acc[nt][1] + acc[nt][2] + acc[nt][3];
    p += __shfl_xor(p, 16);
    p += __shfl_xor(p, 32);
    if (lg == 0) sA[wave][nt * 16 + lrow] = p;
  }

  // C -> LDS (At free after final barrier), then coalesced 16B stores
#pragma unroll
  for (int nt = 0; nt < 10; ++nt)
#pragma unroll
    for (int r = 0; r < 4; ++r) {
      int row = wave * 16 + lg * 4 + r;
      Ct[row * 168 + nt * 16 + lrow] = f2bf(acc[nt][r]);
    }
  __syncthreads();
  if (tid < CD) {
    float s = sA[0][tid] + sA[1][tid] + sA[2][tid] + sA[3][tid];
    partials[(size_t)blockIdx.x * CD + tid] = s;
  }
#pragma unroll
  for (int i = 0; i < 5; ++i) {
    int p = tid + i * 256;                  // 0..1279 pieces of 16B
    int row = p / 20, c0 = (p % 20) * 8;
    *reinterpret_cast<short8v*>(&uhat[(size_t)(row0 + row) * CD + c0]) =
        *reinterpret_cast<const short8v*>(&Ct[row * 168 + c0]);
  }
}

// ---------- squash: per batch, reduce nch chunk-partials, squash ----------
__global__ __launch_bounds__(CD) void squash_k(
    const float* __restrict__ partials, float* __restrict__ vbuf,
    float* __restrict__ outp, float mult, int mode, int nch) {
  int b = blockIdx.x, t = threadIdx.x;
  float s = 0.f;
  for (int ch = 0; ch < nch; ++ch) s += partials[((size_t)b * nch + ch) * CD + t];
  s *= mult;
  float ss = s * s;
  ss += __shfl_xor(ss, 1); ss += __shfl_xor(ss, 2);
  ss += __shfl_xor(ss, 4); ss += __shfl_xor(ss, 8);
  float sn = sqrtf(ss) + 1e-7f;
  float v = s * sn / (1.f + sn * sn);
  size_t o = (size_t)b * CD + t;
  if (mode == 0) vbuf[o] = v;
  else if (mode == 1) vbuf[o] += v;
  else outp[o] = v;
}

// ---------- routing iteration, 16B-vectorized ----------
// 640 thr = 32 row-groups x 20; thread owns 8 consecutive j (ushort8, 16B).
// capsule c = (t%20)/2; pair-reduce via shfl_xor(1). 128 rows/block, grid 1152.
// b = u.V with V = v0 (iter1) or v0+v1 (iter2; b starts at 0 so no b carry).
#define ITER_T 640
__global__ __launch_bounds__(ITER_T) void iter_k(
    const ushort_t* __restrict__ uhat, const float* __restrict__ vbuf,
    float* __restrict__ partials) {
  __shared__ float bv[128][NC];        // 5120 B
  __shared__ float sred[32][CD];       // 20480 B
  const int blk = blockIdx.x;
  const int b = blk / 9, ch = blk % 9;
  const int t = threadIdx.x;
  const int g = t / 20, q = t % 20;
  const int c = q >> 1;
  const ushort_t* ub = uhat + ((size_t)b * NN + ch * 128) * CD + q * 8;

  float v0[8];
  {
    const float* vp = vbuf + (size_t)b * CD + q * 8;
    float4v a = *reinterpret_cast<const float4v*>(vp);
    float4v bb = *reinterpret_cast<const float4v*>(vp + 4);
    v0[0] = a[0]; v0[1] = a[1]; v0[2] = a[2]; v0[3] = a[3];
    v0[4] = bb[0]; v0[5] = bb[1]; v0[6] = bb[2]; v0[7] = bb[3];
  }

  short8v u8[4];
#pragma unroll
  for (int it = 0; it < 4; ++it) {
    int n = g + it * 32;
    u8[it] = *reinterpret_cast<const short8v*>(ub + (size_t)n * CD);
    float p = 0.f;
#pragma unroll
    for (int e = 0; e < 8; ++e) p += bf2f((ushort_t)u8[it][e]) * v0[e];
    p += __shfl_xor(p, 1);
    if ((q & 1) == 0) bv[n][c] = p;
  }
  __syncthreads();

  float a[8];
#pragma unroll
  for (int e = 0; e < 8; ++e) a[e] = 0.f;
#pragma unroll
  for (int it = 0; it < 4; ++it) {
    int n = g + it * 32;
    float bm = bv[n][0];
#pragma unroll
    for (int cc = 1; cc < NC; ++cc) bm = fmaxf(bm, bv[n][cc]);
    float Z = 0.f, mine = 0.f;
#pragma unroll
    for (int cc = 0; cc < NC; ++cc) {
      float e = __expf(bv[n][cc] - bm);
      Z += e;
      if (cc == c) mine = e;
    }
    float w = mine / Z;
#pragma unroll
    for (int e = 0; e < 8; ++e) a[e] += w * bf2f((ushort_t)u8[it][e]);
  }
  {
    float4v* dst0 = reinterpret_cast<float4v*>(&sred[g][q * 8]);
    float4v lo, hi;
    lo[0] = a[0]; lo[1] = a[1]; lo[2] = a[2]; lo[3] = a[3];
    hi[0] = a[4]; hi[1] = a[5]; hi[2] = a[6]; hi[3] = a[7];
    dst0[0] = lo; dst0[1] = hi;
  }
  __syncthreads();
  if (t < CD) {
    float s = 0.f;
#pragma unroll
    for (int gg = 0; gg < 32; ++gg) s += sred[gg][t];
    partials[(size_t)blk * CD + t] = s;
  }
}

extern "C" void kernel_launch(void* const* d_in, const int* in_sizes, int n_in,
                              void* d_out, int out_size, void* d_ws, size_t ws_size,
                              hipStream_t stream) {
  const float* x = (const float*)d_in[0];   // [128,1152,512] f32
  const float* W = (const float*)d_in[1];   // [512,160] f32
  float* out = (float*)d_out;               // [128,10,16] f32

  char* ws = (char*)d_ws;
  ushort_t* uhat     = (ushort_t*)ws;                               // 47,185,920 B
  ushort_t* Wt       = (ushort_t*)(ws + 47185920);                  //    163,840 B
  float*    partials = (float*)(ws + 47185920 + 163840);            //  1,474,560 B
  float*    vbuf     = (float*)(ws + 47185920 + 163840 + 1474560);  //     81,920 B

  wconv<<<320, 256, 0, stream>>>(W, Wt);
  gemm_mfma<<<2304, 256, 0, stream>>>(x, Wt, uhat, partials);
  squash_k<<<BB, CD, 0, stream>>>(partials, vbuf, out, 0.1f, 0, 18);  // v0
  iter_k<<<1152, ITER_T, 0, stream>>>(uhat, vbuf, partials);          // s1 partials
  squash_k<<<BB, CD, 0, stream>>>(partials, vbuf, out, 1.f, 1, 9);    // vbuf = v0+v1
  iter_k<<<1152, ITER_T, 0, stream>>>(uhat, vbuf, partials);          // s2 partials
  squash_k<<<BB, CD, 0, stream>>>(partials, vbuf, out, 1.f, 2, 9);    // out = v2
}

// Round 5
// 136.640 us; speedup vs baseline: 4.5659x; 1.7756x over previous
//
#include <hip/hip_runtime.h>

#define BB 128
#define NN 1152
#define KD 512
#define NC 10
#define ND 16
#define CD 160   // NC*ND

typedef unsigned short ushort_t;
typedef unsigned int uint_t;
typedef short short8v __attribute__((ext_vector_type(8)));
typedef float float4v __attribute__((ext_vector_type(4)));

__device__ __forceinline__ float bf2f(ushort_t u) {
  return __uint_as_float(((uint_t)u) << 16);
}
__device__ __forceinline__ ushort_t f2bf(float f) {
  uint_t x = __float_as_uint(f);
  x += 0x7fffu + ((x >> 16) & 1u);   // round-to-nearest-even
  return (ushort_t)(x >> 16);
}

// ---------- W transpose+convert: Wt[n][k] = bf16(W[k][n]), [160][512] ----------
__global__ __launch_bounds__(256) void wconv(const float* __restrict__ W,
                                             ushort_t* __restrict__ Wt) {
  int idx = blockIdx.x * 256 + threadIdx.x;   // 81920 total
  int n = idx >> 9, k = idx & 511;
  Wt[idx] = f2bf(W[(size_t)k * CD + n]);
}

// ---------- GEMM via MFMA: A+B LDS-staged, double-buffered ----------
// BM=64, BK=64, 256 thr = 4 waves; wave w = rows w*16..+16, all 160 cols.
// Inner loop is pure ds_read_b128 + MFMA. Next-tile global loads issued into
// regs BEFORE compute (latency overlaps MFMA); cvt+ds_write after barrier B.
// Both tiles swizzled: 16B-slot byte ^= (row&7)<<4 (write b128, read b128).
// LDS layout (byte offsets into smem, NO pointer arrays -- addrspacecast):
//   A[buf] @ buf*8192 (64*64 bf16 = 8KB), B[buf] @ 16384 + buf*20480 (20KB).
// Epilogue: C repacked via LDS union -> 16B coalesced stores + passA partials.
__global__ __launch_bounds__(256) void gemm_mfma(
    const float* __restrict__ x, const ushort_t* __restrict__ Wt,
    ushort_t* __restrict__ uhat, float* __restrict__ partials) {
  __shared__ char smem[57344];
  __shared__ float sA[4][CD];
  const int tid = threadIdx.x;
  const int wave = tid >> 6, lane = tid & 63;
  const int lrow = lane & 15, lg = lane >> 4;
  const int row0 = blockIdx.x * 64;

  float4v acc[10];
#pragma unroll
  for (int nt = 0; nt < 10; ++nt)
#pragma unroll
    for (int r = 0; r < 4; ++r) acc[nt][r] = 0.f;

  // ---- A staging coords: 2 pieces, thread covers rows (tid>>3)+{0,32}, slot tid&7
  const int arow_ = tid >> 3;             // 0..31
  const int as = tid & 7;                 // 16B slot
  // ---- B staging coords: 5 pieces f = tid + i*256: row=f>>3 (0..159), slot=f&7
  int bsrc[5], bby[5];
#pragma unroll
  for (int i = 0; i < 5; ++i) {
    int f = tid + i * 256;
    int br = f >> 3, bs = f & 7;
    bsrc[i] = br * KD + bs * 8;                       // element offset (+k0)
    bby[i] = ((br << 7) + (bs << 4)) ^ ((br & 7) << 4);
  }
  const int aby0 = ((arow_ << 7) + (as << 4)) ^ ((arow_ & 7) << 4);
  const int aby1 = (((arow_ + 32) << 7) + (as << 4)) ^ (((arow_ + 32) & 7) << 4);

  float4v rA[2][2];
  short8v rB[5];

  auto LOADS = [&](int ks) {
    int k0 = ks * 64;
#pragma unroll
    for (int i = 0; i < 2; ++i) {
      const float* p = x + (size_t)(row0 + arow_ + i * 32) * KD + k0 + as * 8;
      rA[i][0] = *reinterpret_cast<const float4v*>(p);
      rA[i][1] = *reinterpret_cast<const float4v*>(p + 4);
    }
#pragma unroll
    for (int i = 0; i < 5; ++i)
      rB[i] = *reinterpret_cast<const short8v*>(Wt + bsrc[i] + k0);
  };
  auto WRITES = [&](int buf) {
    char* Ab = smem + buf * 8192;
    char* Bb = smem + 16384 + buf * 20480;
#pragma unroll
    for (int i = 0; i < 2; ++i) {
      short8v pk;
#pragma unroll
      for (int e = 0; e < 4; ++e) {
        pk[e] = (short)f2bf(rA[i][0][e]);
        pk[e + 4] = (short)f2bf(rA[i][1][e]);
      }
      *reinterpret_cast<short8v*>(Ab + (i ? aby1 : aby0)) = pk;
    }
#pragma unroll
    for (int i = 0; i < 5; ++i)
      *reinterpret_cast<short8v*>(Bb + bby[i]) = rB[i];
  };

  const int arow = wave * 16 + lrow;
  LOADS(0);
  WRITES(0);
  int cur = 0;
  for (int ks = 0; ks < 8; ++ks) {
    if (ks < 7) LOADS(ks + 1);
    __syncthreads();                     // buf[cur] writes visible
    const char* Ab = smem + cur * 8192;
    const char* Bb = smem + 16384 + cur * 20480;
#pragma unroll
    for (int kk = 0; kk < 2; ++kk) {
      int abyte = ((arow << 7) + kk * 64 + lg * 16) ^ ((arow & 7) << 4);
      short8v a = *reinterpret_cast<const short8v*>(Ab + abyte);
#pragma unroll
      for (int nt = 0; nt < 10; ++nt) {
        int brow = nt * 16 + lrow;
        int bbyte = ((brow << 7) + kk * 64 + lg * 16) ^ ((brow & 7) << 4);
        short8v bfr = *reinterpret_cast<const short8v*>(Bb + bbyte);
        acc[nt] = __builtin_amdgcn_mfma_f32_16x16x32_bf16(a, bfr, acc[nt], 0, 0, 0);
      }
    }
    __syncthreads();                     // all reads of buf[cur] done
    if (ks < 7) WRITES(cur ^ 1);
    cur ^= 1;
  }

  // ---- passA partials: col-sums over this block's 64 rows
#pragma unroll
  for (int nt = 0; nt < 10; ++nt) {
    float p = acc[nt][0] + acc[nt][1] + acc[nt][2] + acc[nt][3];
    p += __shfl_xor(p, 16);
    p += __shfl_xor(p, 32);
    if (lg == 0) sA[wave][nt * 16 + lrow] = p;
  }

  // ---- C repack through LDS union -> coalesced 16B stores
  ushort_t* Ct = reinterpret_cast<ushort_t*>(smem);     // [64][168]
#pragma unroll
  for (int nt = 0; nt < 10; ++nt)
#pragma unroll
    for (int r = 0; r < 4; ++r) {
      int row = wave * 16 + lg * 4 + r;
      Ct[row * 168 + nt * 16 + lrow] = f2bf(acc[nt][r]);
    }
  __syncthreads();
  if (tid < CD) {
    float s = sA[0][tid] + sA[1][tid] + sA[2][tid] + sA[3][tid];
    partials[(size_t)blockIdx.x * CD + tid] = s;
  }
#pragma unroll
  for (int i = 0; i < 5; ++i) {
    int p = tid + i * 256;                  // 1280 pieces of 16B
    int row = p / 20, c0 = (p % 20) * 8;
    *reinterpret_cast<short8v*>(&uhat[(size_t)(row0 + row) * CD + c0]) =
        *reinterpret_cast<const short8v*>(&Ct[row * 168 + c0]);
  }
}

// ---------- squash: per batch, reduce nch chunk-partials, squash ----------
__global__ __launch_bounds__(CD) void squash_k(
    const float* __restrict__ partials, float* __restrict__ vbuf,
    float* __restrict__ outp, float mult, int mode, int nch) {
  int b = blockIdx.x, t = threadIdx.x;
  float s = 0.f;
  for (int ch = 0; ch < nch; ++ch) s += partials[((size_t)b * nch + ch) * CD + t];
  s *= mult;
  float ss = s * s;
  ss += __shfl_xor(ss, 1); ss += __shfl_xor(ss, 2);
  ss += __shfl_xor(ss, 4); ss += __shfl_xor(ss, 8);
  float sn = sqrtf(ss) + 1e-7f;
  float v = s * sn / (1.f + sn * sn);
  size_t o = (size_t)b * CD + t;
  if (mode == 0) vbuf[o] = v;
  else if (mode == 1) vbuf[o] += v;
  else outp[o] = v;
}

// ---------- routing iteration, 16B-vectorized ----------
// 640 thr = 32 row-groups x 20; thread owns 8 consecutive j (16B loads).
// b = u.V with V = v0 (iter1) or v0+v1 (iter2; b starts at 0, no b carry).
// Final col-reduce parallelized 640-wide (4 parts x 8 groups) then 4-way.
#define ITER_T 640
__global__ __launch_bounds__(ITER_T) void iter_k(
    const ushort_t* __restrict__ uhat, const float* __restrict__ vbuf,
    float* __restrict__ partials) {
  __shared__ float bv[128][NC];        // 5120 B
  __shared__ float sred[32][CD];       // 20480 B
  __shared__ float sred2[4][CD];       // 2560 B
  const int blk = blockIdx.x;
  const int b = blk / 9, ch = blk % 9;
  const int t = threadIdx.x;
  const int g = t / 20, q = t % 20;
  const int c = q >> 1;
  const ushort_t* ub = uhat + ((size_t)b * NN + ch * 128) * CD + q * 8;

  float v0[8];
  {
    const float* vp = vbuf + (size_t)b * CD + q * 8;
    float4v a = *reinterpret_cast<const float4v*>(vp);
    float4v bb = *reinterpret_cast<const float4v*>(vp + 4);
#pragma unroll
    for (int e = 0; e < 4; ++e) { v0[e] = a[e]; v0[e + 4] = bb[e]; }
  }

  short8v u8[4];
#pragma unroll
  for (int it = 0; it < 4; ++it) {
    int n = g + it * 32;
    u8[it] = *reinterpret_cast<const short8v*>(ub + (size_t)n * CD);
    float p = 0.f;
#pragma unroll
    for (int e = 0; e < 8; ++e) p += bf2f((ushort_t)u8[it][e]) * v0[e];
    p += __shfl_xor(p, 1);
    if ((q & 1) == 0) bv[n][c] = p;
  }
  __syncthreads();

  float a[8];
#pragma unroll
  for (int e = 0; e < 8; ++e) a[e] = 0.f;
#pragma unroll
  for (int it = 0; it < 4; ++it) {
    int n = g + it * 32;
    float bm = bv[n][0];
#pragma unroll
    for (int cc = 1; cc < NC; ++cc) bm = fmaxf(bm, bv[n][cc]);
    float Z = 0.f, mine = 0.f;
#pragma unroll
    for (int cc = 0; cc < NC; ++cc) {
      float e = __expf(bv[n][cc] - bm);
      Z += e;
      if (cc == c) mine = e;
    }
    float w = mine / Z;
#pragma unroll
    for (int e = 0; e < 8; ++e) a[e] += w * bf2f((ushort_t)u8[it][e]);
  }
  {
    float4v lo, hi;
#pragma unroll
    for (int e = 0; e < 4; ++e) { lo[e] = a[e]; hi[e] = a[e + 4]; }
    float4v* dst = reinterpret_cast<float4v*>(&sred[g][q * 8]);
    dst[0] = lo; dst[1] = hi;
  }
  __syncthreads();
  {
    int col = t % CD, part = t / CD;    // 640 = 4 x 160
    float s = 0.f;
#pragma unroll
    for (int g8 = 0; g8 < 8; ++g8) s += sred[part * 8 + g8][col];
    sred2[part][col] = s;
  }
  __syncthreads();
  if (t < CD) {
    partials[(size_t)blk * CD + t] =
        sred2[0][t] + sred2[1][t] + sred2[2][t] + sred2[3][t];
  }
}

extern "C" void kernel_launch(void* const* d_in, const int* in_sizes, int n_in,
                              void* d_out, int out_size, void* d_ws, size_t ws_size,
                              hipStream_t stream) {
  const float* x = (const float*)d_in[0];   // [128,1152,512] f32
  const float* W = (const float*)d_in[1];   // [512,160] f32
  float* out = (float*)d_out;               // [128,10,16] f32

  char* ws = (char*)d_ws;
  ushort_t* uhat     = (ushort_t*)ws;                               // 47,185,920 B
  ushort_t* Wt       = (ushort_t*)(ws + 47185920);                  //    163,840 B
  float*    partials = (float*)(ws + 47185920 + 163840);            //  1,474,560 B
  float*    vbuf     = (float*)(ws + 47185920 + 163840 + 1474560);  //     81,920 B

  wconv<<<320, 256, 0, stream>>>(W, Wt);
  gemm_mfma<<<2304, 256, 0, stream>>>(x, Wt, uhat, partials);
  squash_k<<<BB, CD, 0, stream>>>(partials, vbuf, out, 0.1f, 0, 18);  // v0
  iter_k<<<1152, ITER_T, 0, stream>>>(uhat, vbuf, partials);          // s1 partials
  squash_k<<<BB, CD, 0, stream>>>(partials, vbuf, out, 1.f, 1, 9);    // vbuf = v0+v1
  iter_k<<<1152, ITER_T, 0, stream>>>(uhat, vbuf, partials);          // s2 partials
  squash_k<<<BB, CD, 0, stream>>>(partials, vbuf, out, 1.f, 2, 9);    // out = v2
}

// Round 6
// 109.779 us; speedup vs baseline: 5.6831x; 1.2447x over previous
//
#include <hip/hip_runtime.h>

#define BB 128
#define NN 1152
#define KD 512
#define NC 10
#define ND 16
#define CD 160   // NC*ND

typedef unsigned short ushort_t;
typedef unsigned int uint_t;
typedef short short8v __attribute__((ext_vector_type(8)));
typedef float float4v __attribute__((ext_vector_type(4)));

__device__ __forceinline__ float bf2f(ushort_t u) {
  return __uint_as_float(((uint_t)u) << 16);
}
__device__ __forceinline__ ushort_t f2bf(float f) {
  uint_t x = __float_as_uint(f);
  x += 0x7fffu + ((x >> 16) & 1u);   // round-to-nearest-even
  return (ushort_t)(x >> 16);
}

// Barrier that does NOT drain vmcnt: LDS-visibility (lgkmcnt) only.
// Keeps global register-prefetch loads in flight across k-step barriers.
// sched_barrier(0) fences per cdna guide rule #18.
#define BAR_LDS() do {                                   \
    __builtin_amdgcn_sched_barrier(0);                   \
    asm volatile("s_waitcnt lgkmcnt(0)" ::: "memory");   \
    __builtin_amdgcn_s_barrier();                        \
    __builtin_amdgcn_sched_barrier(0);                   \
  } while (0)

// ---------- W transpose+convert: Wt[n][k] = bf16(W[k][n]), [160][512] ----------
__global__ __launch_bounds__(256) void wconv(const float* __restrict__ W,
                                             ushort_t* __restrict__ Wt) {
  int idx = blockIdx.x * 256 + threadIdx.x;   // 81920 total
  int n = idx >> 9, k = idx & 511;
  Wt[idx] = f2bf(W[(size_t)k * CD + n]);
}

// ---------- GEMM via MFMA: A+B LDS-staged, double-buffered ----------
// BM=64, BK=64, 256 thr = 4 waves; wave w = rows w*16..+16, all 160 cols.
// ONE lgkmcnt-only barrier per k-step; vmcnt never drained at barriers so
// next-tile register prefetches overlap compute. Swizzle byte ^= (row&7)<<4.
// LDS: A[buf] @ buf*8192 (8KB), B[buf] @ 16384 + buf*20480 (20KB). 57KB.
__global__ __launch_bounds__(256) void gemm_mfma(
    const float* __restrict__ x, const ushort_t* __restrict__ Wt,
    ushort_t* __restrict__ uhat, float* __restrict__ partials) {
  __shared__ char smem[57344];
  __shared__ float sA[4][CD];
  const int tid = threadIdx.x;
  const int wave = tid >> 6, lane = tid & 63;
  const int lrow = lane & 15, lg = lane >> 4;
  const int row0 = blockIdx.x * 64;

  float4v acc[10];
#pragma unroll
  for (int nt = 0; nt < 10; ++nt)
#pragma unroll
    for (int r = 0; r < 4; ++r) acc[nt][r] = 0.f;

  const int arow_ = tid >> 3;             // 0..31
  const int as = tid & 7;                 // 16B slot
  int bsrc[5], bby[5];
#pragma unroll
  for (int i = 0; i < 5; ++i) {
    int f = tid + i * 256;
    int br = f >> 3, bs = f & 7;
    bsrc[i] = br * KD + bs * 8;
    bby[i] = ((br << 7) + (bs << 4)) ^ ((br & 7) << 4);
  }
  const int aby0 = ((arow_ << 7) + (as << 4)) ^ ((arow_ & 7) << 4);
  const int aby1 = (((arow_ + 32) << 7) + (as << 4)) ^ (((arow_ + 32) & 7) << 4);

  float4v rA[2][2];
  short8v rB[5];

  auto LOADS = [&](int ks) {
    int k0 = ks * 64;
#pragma unroll
    for (int i = 0; i < 2; ++i) {
      const float* p = x + (size_t)(row0 + arow_ + i * 32) * KD + k0 + as * 8;
      rA[i][0] = *reinterpret_cast<const float4v*>(p);
      rA[i][1] = *reinterpret_cast<const float4v*>(p + 4);
    }
#pragma unroll
    for (int i = 0; i < 5; ++i)
      rB[i] = *reinterpret_cast<const short8v*>(Wt + bsrc[i] + k0);
  };
  auto WRITES = [&](int buf) {
    char* Ab = smem + buf * 8192;
    char* Bb = smem + 16384 + buf * 20480;
#pragma unroll
    for (int i = 0; i < 2; ++i) {
      short8v pk;
#pragma unroll
      for (int e = 0; e < 4; ++e) {
        pk[e] = (short)f2bf(rA[i][0][e]);
        pk[e + 4] = (short)f2bf(rA[i][1][e]);
      }
      *reinterpret_cast<short8v*>(Ab + (i ? aby1 : aby0)) = pk;
    }
#pragma unroll
    for (int i = 0; i < 5; ++i)
      *reinterpret_cast<short8v*>(Bb + bby[i]) = rB[i];
  };

  const int arow = wave * 16 + lrow;
  LOADS(0);
  WRITES(0);
  LOADS(1);
  BAR_LDS();                             // tile 0 visible
  int cur = 0;
  for (int ks = 0; ks < 8; ++ks) {
    const char* Ab = smem + cur * 8192;
    const char* Bb = smem + 16384 + cur * 20480;
#pragma unroll
    for (int kk = 0; kk < 2; ++kk) {
      int abyte = ((arow << 7) + kk * 64 + lg * 16) ^ ((arow & 7) << 4);
      short8v a = *reinterpret_cast<const short8v*>(Ab + abyte);
#pragma unroll
      for (int nt = 0; nt < 10; ++nt) {
        int brow = nt * 16 + lrow;
        int bbyte = ((brow << 7) + kk * 64 + lg * 16) ^ ((brow & 7) << 4);
        short8v bfr = *reinterpret_cast<const short8v*>(Bb + bbyte);
        acc[nt] = __builtin_amdgcn_mfma_f32_16x16x32_bf16(a, bfr, acc[nt], 0, 0, 0);
      }
    }
    if (ks < 7) {
      WRITES(cur ^ 1);                   // tile ks+1 -> other buf (reads of it
      if (ks < 6) LOADS(ks + 2);         //  finished before prev barrier)
    }
    BAR_LDS();                           // my reads+writes retired; tile ks+1 visible
    cur ^= 1;
  }

  // ---- passA partials: col-sums over this block's 64 rows
#pragma unroll
  for (int nt = 0; nt < 10; ++nt) {
    float p = acc[nt][0] + acc[nt][1] + acc[nt][2] + acc[nt][3];
    p += __shfl_xor(p, 16);
    p += __shfl_xor(p, 32);
    if (lg == 0) sA[wave][nt * 16 + lrow] = p;
  }

  // ---- C repack through LDS union -> coalesced 16B stores
  ushort_t* Ct = reinterpret_cast<ushort_t*>(smem);     // [64][168]
#pragma unroll
  for (int nt = 0; nt < 10; ++nt)
#pragma unroll
    for (int r = 0; r < 4; ++r) {
      int row = wave * 16 + lg * 4 + r;
      Ct[row * 168 + nt * 16 + lrow] = f2bf(acc[nt][r]);
    }
  __syncthreads();
  if (tid < CD) {
    float s = sA[0][tid] + sA[1][tid] + sA[2][tid] + sA[3][tid];
    partials[(size_t)blockIdx.x * CD + tid] = s;
  }
#pragma unroll
  for (int i = 0; i < 5; ++i) {
    int p = tid + i * 256;
    int row = p / 20, c0 = (p % 20) * 8;
    *reinterpret_cast<short8v*>(&uhat[(size_t)(row0 + row) * CD + c0]) =
        *reinterpret_cast<const short8v*>(&Ct[row * 168 + c0]);
  }
}

// ---------- routing iteration with fused v-computation ----------
// Prologue: vv = v0 = squash(0.1*sum(pg 18 chunks)); ITER2 adds v1 = squash(sum(p1)).
// Phase 1: b[n][c] = u.vv; Phase 1.5: softmax weights ONCE per row into LDS;
// Phase 2: accumulate s partials. 640 thr = 32 row-groups x 20 (8 cols each).
#define ITER_T 640
template <int ITER2>
__global__ __launch_bounds__(ITER_T) void iter_k(
    const ushort_t* __restrict__ uhat, const float* __restrict__ pg,
    const float* __restrict__ p1, float* __restrict__ pout) {
  __shared__ float bv[128][NC];        // 5120 B
  __shared__ float wv[128][NC];        // 5120 B
  __shared__ float sred[32][CD];       // 20480 B
  __shared__ float sred2[4][CD];       // 2560 B
  __shared__ float vv[CD];             // 640 B
  const int blk = blockIdx.x;
  const int b = blk / 9, ch = blk % 9;
  const int t = threadIdx.x;
  const int g = t / 20, q = t % 20;
  const int c = q >> 1;
  const ushort_t* ub = uhat + ((size_t)b * NN + ch * 128) * CD + q * 8;

  // ---- prologue: compute vv (= v0, or v0+v1 for ITER2)
  if (t < CD) {
    float s0 = 0.f;
#pragma unroll
    for (int cc = 0; cc < 18; ++cc) s0 += pg[((size_t)b * 18 + cc) * CD + t];
    s0 *= 0.1f;
    float ss = s0 * s0;
    ss += __shfl_xor(ss, 1); ss += __shfl_xor(ss, 2);
    ss += __shfl_xor(ss, 4); ss += __shfl_xor(ss, 8);
    float sn = sqrtf(ss) + 1e-7f;
    float v = s0 * sn / (1.f + sn * sn);
    if (ITER2) {
      float s1 = 0.f;
#pragma unroll
      for (int cc = 0; cc < 9; ++cc) s1 += p1[((size_t)b * 9 + cc) * CD + t];
      float ss1 = s1 * s1;
      ss1 += __shfl_xor(ss1, 1); ss1 += __shfl_xor(ss1, 2);
      ss1 += __shfl_xor(ss1, 4); ss1 += __shfl_xor(ss1, 8);
      float sn1 = sqrtf(ss1) + 1e-7f;
      v += s1 * sn1 / (1.f + sn1 * sn1);
    }
    vv[t] = v;
  }
  __syncthreads();

  float v0r[8];
  {
    float4v a = *reinterpret_cast<const float4v*>(&vv[q * 8]);
    float4v bb = *reinterpret_cast<const float4v*>(&vv[q * 8 + 4]);
#pragma unroll
    for (int e = 0; e < 4; ++e) { v0r[e] = a[e]; v0r[e + 4] = bb[e]; }
  }

  // ---- phase 1: logits
  short8v u8[4];
#pragma unroll
  for (int it = 0; it < 4; ++it) {
    int n = g + it * 32;
    u8[it] = *reinterpret_cast<const short8v*>(ub + (size_t)n * CD);
    float p = 0.f;
#pragma unroll
    for (int e = 0; e < 8; ++e) p += bf2f((ushort_t)u8[it][e]) * v0r[e];
    p += __shfl_xor(p, 1);
    if ((q & 1) == 0) bv[n][c] = p;
  }
  __syncthreads();

  // ---- phase 1.5: softmax weights once per row
  if (t < 128) {
    float e[NC];
    float bm = bv[t][0];
#pragma unroll
    for (int cc = 1; cc < NC; ++cc) bm = fmaxf(bm, bv[t][cc]);
    float Z = 0.f;
#pragma unroll
    for (int cc = 0; cc < NC; ++cc) { e[cc] = __expf(bv[t][cc] - bm); Z += e[cc]; }
    float rz = 1.f / Z;
#pragma unroll
    for (int cc = 0; cc < NC; ++cc) wv[t][cc] = e[cc] * rz;
  }
  __syncthreads();

  // ---- phase 2: weighted accumulate
  float a[8];
#pragma unroll
  for (int e = 0; e < 8; ++e) a[e] = 0.f;
#pragma unroll
  for (int it = 0; it < 4; ++it) {
    int n = g + it * 32;
    float w = wv[n][c];
#pragma unroll
    for (int e = 0; e < 8; ++e) a[e] += w * bf2f((ushort_t)u8[it][e]);
  }
  {
    float4v lo, hi;
#pragma unroll
    for (int e = 0; e < 4; ++e) { lo[e] = a[e]; hi[e] = a[e + 4]; }
    float4v* dst = reinterpret_cast<float4v*>(&sred[g][q * 8]);
    dst[0] = lo; dst[1] = hi;
  }
  __syncthreads();
  {
    int col = t % CD, part = t / CD;    // 640 = 4 x 160
    float s = 0.f;
#pragma unroll
    for (int g8 = 0; g8 < 8; ++g8) s += sred[part * 8 + g8][col];
    sred2[part][col] = s;
  }
  __syncthreads();
  if (t < CD) {
    pout[(size_t)blk * CD + t] =
        sred2[0][t] + sred2[1][t] + sred2[2][t] + sred2[3][t];
  }
}

// ---------- final squash: v2 = squash(sum of 9 iter2 partials) -> out ----------
__global__ __launch_bounds__(CD) void squash_out(
    const float* __restrict__ p2, float* __restrict__ outp) {
  int b = blockIdx.x, t = threadIdx.x;
  float s = 0.f;
#pragma unroll
  for (int cc = 0; cc < 9; ++cc) s += p2[((size_t)b * 9 + cc) * CD + t];
  float ss = s * s;
  ss += __shfl_xor(ss, 1); ss += __shfl_xor(ss, 2);
  ss += __shfl_xor(ss, 4); ss += __shfl_xor(ss, 8);
  float sn = sqrtf(ss) + 1e-7f;
  outp[(size_t)b * CD + t] = s * sn / (1.f + sn * sn);
}

extern "C" void kernel_launch(void* const* d_in, const int* in_sizes, int n_in,
                              void* d_out, int out_size, void* d_ws, size_t ws_size,
                              hipStream_t stream) {
  const float* x = (const float*)d_in[0];   // [128,1152,512] f32
  const float* W = (const float*)d_in[1];   // [512,160] f32
  float* out = (float*)d_out;               // [128,10,16] f32

  char* ws = (char*)d_ws;
  ushort_t* uhat = (ushort_t*)ws;                          // 47,185,920 B
  ushort_t* Wt   = (ushort_t*)(ws + 47185920);             //    163,840 B
  float*    pg   = (float*)(ws + 47185920 + 163840);       //  1,474,560 B  [2304][160]
  float*    p1   = (float*)(ws + 48824320);                //    737,280 B  [1152][160]
  float*    p2   = (float*)(ws + 49561600);                //    737,280 B  [1152][160]

  wconv<<<320, 256, 0, stream>>>(W, Wt);
  gemm_mfma<<<2304, 256, 0, stream>>>(x, Wt, uhat, pg);
  iter_k<0><<<1152, ITER_T, 0, stream>>>(uhat, pg, nullptr, p1);  // s1 partials
  iter_k<1><<<1152, ITER_T, 0, stream>>>(uhat, pg, p1, p2);       // s2 partials
  squash_out<<<BB, CD, 0, stream>>>(p2, out);                     // out = v2
}